// Round 1
// baseline (1064.745 us; speedup 1.0000x reference)
//
#include <hip/hip_runtime.h>
#include <math.h>

// Problem constants (B=2, H=16, L=2048, D=128, fp32 in/out, int32 mask)
constexpr int Bc_ = 2;
constexpr int Hc_ = 16;
constexpr int Lc_ = 2048;
constexpr int Dc_ = 128;
constexpr int BR  = 64;   // Q rows per block (4 waves x 16)
constexpr int BC  = 32;   // K rows per tile
constexpr float SCALE = 0.08838834764831845f;  // 1/sqrt(128)
constexpr float NEGV  = -10000.0f;

typedef __attribute__((ext_vector_type(8))) short          bf16x8;  // MFMA A/B frag (8 bf16 = 4 VGPR)
typedef __attribute__((ext_vector_type(8))) unsigned short u16x8;
typedef __attribute__((ext_vector_type(4))) float          f32x4;   // MFMA C/D frag

// fp32 -> bf16 round-to-nearest-even
__device__ __forceinline__ unsigned short f2bf(float f) {
  unsigned u = __builtin_bit_cast(unsigned, f);
  return (unsigned short)((u + 0x7fffu + ((u >> 16) & 1u)) >> 16);
}

// LDS strides (elements). Ks: +8 pad -> 4-word bank shift/row (2-way max on b128 reads).
// Vt: 72 -> 16B-aligned rows, 36-word shift/row. Ps: 40 -> 20-word shift/row.
constexpr int KS_STRIDE = 136;
constexpr int VT_STRIDE = 72;
constexpr int PS_STRIDE = 40;

__global__ __launch_bounds__(256, 4) void attn_fwd(
    const float* __restrict__ Q, const float* __restrict__ K,
    const float* __restrict__ V, const int* __restrict__ Mask,
    float* __restrict__ Out) {
  const int qblk = blockIdx.x;     // 0..31  (q tile)
  const int bh   = blockIdx.y;     // 0..31  (batch*head)
  const int tid  = threadIdx.x;
  const int w    = tid >> 6;       // wave 0..3
  const int lane = tid & 63;
  const int t16  = lane & 15;
  const int quad = lane >> 4;

  const float* Qg = Q    + (size_t)bh * Lc_ * Dc_;
  const float* Kg = K    + (size_t)bh * Lc_ * Dc_;
  const float* Vg = V    + (size_t)bh * Lc_ * Dc_;
  const int*   Mg = Mask + (size_t)bh * Lc_ * Lc_;
  float*       Og = Out  + (size_t)bh * Lc_ * Dc_;

  const int qr0 = qblk * BR + w * 16;  // this wave's first Q row

  __shared__ alignas(16) unsigned short Ks[BC * KS_STRIDE];        // K tile, row-major bf16
  __shared__ alignas(16) unsigned short Vt[Dc_ * VT_STRIDE];       // V tile, transposed [d][k]
  __shared__ alignas(16) unsigned short Ps[4 * 16 * PS_STRIDE];    // per-wave P (16x32) staging

  // ---- Q fragments (A-operand), loaded once, pre-scaled by 1/sqrt(D) ----
  // A[m=lane&15][k=quad*8+j]; 4 K-steps of 32 cover D=128.
  bf16x8 qf[4];
  {
    const float* qrow = Qg + (size_t)(qr0 + t16) * Dc_ + quad * 8;
#pragma unroll
    for (int s = 0; s < 4; ++s) {
      const f32x4 a = *(const f32x4*)(qrow + s * 32);
      const f32x4 b = *(const f32x4*)(qrow + s * 32 + 4);
      bf16x8 f;
      f[0] = (short)f2bf(a[0] * SCALE); f[1] = (short)f2bf(a[1] * SCALE);
      f[2] = (short)f2bf(a[2] * SCALE); f[3] = (short)f2bf(a[3] * SCALE);
      f[4] = (short)f2bf(b[0] * SCALE); f[5] = (short)f2bf(b[1] * SCALE);
      f[6] = (short)f2bf(b[2] * SCALE); f[7] = (short)f2bf(b[3] * SCALE);
      qf[s] = f;
    }
  }

  f32x4 acc[8];            // O accumulator: 16 rows x 128 cols (C-layout per 16-col block)
#pragma unroll
  for (int i = 0; i < 8; ++i) acc[i] = (f32x4)0.0f;
  float mstate[4] = {-INFINITY, -INFINITY, -INFINITY, -INFINITY};
  float lstate[4] = {0.f, 0.f, 0.f, 0.f};

  // Staging thread mappings
  const int krow = tid >> 3;   // 0..31, 8 threads/row (coalesced 64B groups)
  const int kcg  = tid & 7;    // col group *16
  const int vrow = tid & 31;   // 0..31 (k index) -> scatter writes land in distinct words
  const int vcg  = tid >> 5;   // 0..7

#pragma unroll 1
  for (int kb = 0; kb < Lc_; kb += BC) {
    __syncthreads();  // previous tile fully consumed before overwrite

    // ---- stage K tile: 32x128 fp32 -> bf16 rows ----
    {
      const float* kr = Kg + (size_t)(kb + krow) * Dc_ + kcg * 16;
      f32x4 k0 = *(const f32x4*)(kr + 0);
      f32x4 k1 = *(const f32x4*)(kr + 4);
      f32x4 k2 = *(const f32x4*)(kr + 8);
      f32x4 k3 = *(const f32x4*)(kr + 12);
      u16x8 p0, p1;
      p0[0]=f2bf(k0[0]); p0[1]=f2bf(k0[1]); p0[2]=f2bf(k0[2]); p0[3]=f2bf(k0[3]);
      p0[4]=f2bf(k1[0]); p0[5]=f2bf(k1[1]); p0[6]=f2bf(k1[2]); p0[7]=f2bf(k1[3]);
      p1[0]=f2bf(k2[0]); p1[1]=f2bf(k2[1]); p1[2]=f2bf(k2[2]); p1[3]=f2bf(k2[3]);
      p1[4]=f2bf(k3[0]); p1[5]=f2bf(k3[1]); p1[6]=f2bf(k3[2]); p1[7]=f2bf(k3[3]);
      *(u16x8*)&Ks[krow * KS_STRIDE + kcg * 16]     = p0;
      *(u16x8*)&Ks[krow * KS_STRIDE + kcg * 16 + 8] = p1;
    }
    // ---- stage V tile transposed: Vt[d][k] bf16 ----
    {
      const float* vr = Vg + (size_t)(kb + vrow) * Dc_ + vcg * 16;
#pragma unroll
      for (int c = 0; c < 16; c += 4) {
        f32x4 vv = *(const f32x4*)(vr + c);
        Vt[(vcg * 16 + c + 0) * VT_STRIDE + vrow] = f2bf(vv[0]);
        Vt[(vcg * 16 + c + 1) * VT_STRIDE + vrow] = f2bf(vv[1]);
        Vt[(vcg * 16 + c + 2) * VT_STRIDE + vrow] = f2bf(vv[2]);
        Vt[(vcg * 16 + c + 3) * VT_STRIDE + vrow] = f2bf(vv[3]);
      }
    }
    __syncthreads();

    // ---- S = (Q*scale) K^T : two 16x16 blocks ----
    f32x4 sblk[2];
#pragma unroll
    for (int blk = 0; blk < 2; ++blk) {
      f32x4 s = (f32x4)0.0f;
      const unsigned short* kbase = &Ks[(blk * 16 + t16) * KS_STRIDE + quad * 8];
#pragma unroll
      for (int st = 0; st < 4; ++st) {
        bf16x8 bf = *(const bf16x8*)(kbase + st * 32);
        s = __builtin_amdgcn_mfma_f32_16x16x32_bf16(qf[st], bf, s, 0, 0, 0);
      }
      sblk[blk] = s;
    }

    // ---- mask + online softmax (row r lives in lanes of this quad) ----
    const int mrow0 = qr0 + quad * 4;
#pragma unroll
    for (int r = 0; r < 4; ++r) {
      const int* mrow = Mg + (size_t)(mrow0 + r) * Lc_ + kb;
      const int m0 = mrow[t16];
      const int m1 = mrow[16 + t16];
      float s0 = (m0 == 0) ? NEGV : sblk[0][r];
      float s1 = (m1 == 0) ? NEGV : sblk[1][r];
      float rowmax = fmaxf(s0, s1);
      rowmax = fmaxf(rowmax, __shfl_xor(rowmax, 1));
      rowmax = fmaxf(rowmax, __shfl_xor(rowmax, 2));
      rowmax = fmaxf(rowmax, __shfl_xor(rowmax, 4));
      rowmax = fmaxf(rowmax, __shfl_xor(rowmax, 8));
      const float mnew  = fmaxf(mstate[r], rowmax);
      const float alpha = __expf(mstate[r] - mnew);   // exp(-inf)=0 on first tile
      const float p0 = __expf(s0 - mnew);
      const float p1 = __expf(s1 - mnew);
      float rs = p0 + p1;
      rs += __shfl_xor(rs, 1);
      rs += __shfl_xor(rs, 2);
      rs += __shfl_xor(rs, 4);
      rs += __shfl_xor(rs, 8);
      lstate[r] = lstate[r] * alpha + rs;
      mstate[r] = mnew;
#pragma unroll
      for (int nb = 0; nb < 8; ++nb) acc[nb][r] *= alpha;
      // P (C-layout) -> LDS for A-layout reread
      unsigned short* prow = &Ps[(w * 16 + quad * 4 + r) * PS_STRIDE];
      prow[t16]      = f2bf(p0);
      prow[16 + t16] = f2bf(p1);
    }

    // ---- O += P * V ----
    const bf16x8 pf = *(const bf16x8*)&Ps[(w * 16 + t16) * PS_STRIDE + quad * 8];
#pragma unroll
    for (int nb = 0; nb < 8; ++nb) {
      bf16x8 vf = *(const bf16x8*)&Vt[(nb * 16 + t16) * VT_STRIDE + quad * 8];
      acc[nb] = __builtin_amdgcn_mfma_f32_16x16x32_bf16(pf, vf, acc[nb], 0, 0, 0);
    }
  }

  // ---- epilogue: O / l ----
#pragma unroll
  for (int r = 0; r < 4; ++r) {
    const float inv = 1.0f / lstate[r];
    float* orow = Og + (size_t)(qr0 + quad * 4 + r) * Dc_ + t16;
#pragma unroll
    for (int nb = 0; nb < 8; ++nb) orow[nb * 16] = acc[nb][r] * inv;
  }
}

extern "C" void kernel_launch(void* const* d_in, const int* in_sizes, int n_in,
                              void* d_out, int out_size, void* d_ws, size_t ws_size,
                              hipStream_t stream) {
  const float* Q    = (const float*)d_in[0];
  const float* K    = (const float*)d_in[1];
  const float* V    = (const float*)d_in[2];
  const int*   Mask = (const int*)d_in[3];
  float*       Out  = (float*)d_out;
  dim3 grid(Lc_ / BR, Bc_ * Hc_);
  attn_fwd<<<grid, dim3(256), 0, stream>>>(Q, K, V, Mask, Out);
}